// Round 5
// baseline (263.119 us; speedup 1.0000x reference)
//
#include <hip/hip_runtime.h>
#include <hip/hip_bf16.h>

// Problem: B=4, C=256, N=4096 (16^3).
// out[b,c,n] = sum_m relu(cos(x_n,x_m))^2 * (W x + b)[c,m]
// Decomposition: xn = x/||x|| (bf16) -> S = xn^T xn, P = relu(S)^2,
//                T[c,m] = nrm[m]*(W xn)[c,m] + b[c],   out = T * P^T.

typedef unsigned short u16;
typedef __attribute__((ext_vector_type(8))) short short8;   // 8 bf16 = 4 VGPRs
typedef __attribute__((ext_vector_type(4))) float f32x4;

#define MFMA16(a, b, c) __builtin_amdgcn_mfma_f32_16x16x32_bf16((a), (b), (c), 0, 0, 0)

__device__ __forceinline__ u16 f2bf(float f) {
    union { float f; unsigned u; } v; v.f = f;
    unsigned u = v.u;
    u += 0x7fffu + ((u >> 16) & 1u);   // RNE
    return (u16)(u >> 16);
}

// ------- K1: fused norm + transpose + W-convert: one read of x ---------------
__global__ __launch_bounds__(256) void k_prep(const float* __restrict__ x,
                                              const float* __restrict__ W,
                                              u16* __restrict__ xfn,
                                              u16* __restrict__ Wbf,
                                              float* __restrict__ nrm) {
    __shared__ float xs[256][65];     // 65 pad: conflict-free col reads
    __shared__ float part[4][64];
    __shared__ float rs_s[64];
    int bid = blockIdx.x;
    int b = bid >> 6, n0 = (bid & 63) << 6;
    int tid = threadIdx.x;
    int wi = (bid << 8) + tid;
    Wbf[wi] = f2bf(W[wi]);
    int rowg = tid >> 4, l16 = tid & 15;
    const float* xb = x + ((size_t)b << 20) + n0;
#pragma unroll
    for (int s = 0; s < 16; ++s) {
        int row = (s << 4) + rowg;    // c index
        float4 v = *(const float4*)(xb + (size_t)row * 4096 + (l16 << 2));
        xs[row][(l16 << 2) + 0] = v.x;
        xs[row][(l16 << 2) + 1] = v.y;
        xs[row][(l16 << 2) + 2] = v.z;
        xs[row][(l16 << 2) + 3] = v.w;
    }
    __syncthreads();
    int q = tid >> 6, nl = tid & 63;
    float ss = 0.f;
#pragma unroll 16
    for (int c = 0; c < 64; ++c) {
        float v = xs[(q << 6) + c][nl];
        ss += v * v;
    }
    part[q][nl] = ss;
    __syncthreads();
    if (tid < 64) {
        float t = part[0][tid] + part[1][tid] + part[2][tid] + part[3][tid];
        float nr = sqrtf(t);
        nrm[(b << 12) + n0 + tid] = nr;
        rs_s[tid] = 1.0f / fmaxf(nr, 1e-8f);
    }
    __syncthreads();
    u16* op = xfn + ((size_t)b << 20) + (size_t)n0 * 256;
#pragma unroll
    for (int s2 = 0; s2 < 4; ++s2) {
        int n = (s2 << 4) + rowg;
        float rsv = rs_s[n];
        u16 tmp[16];
#pragma unroll
        for (int j = 0; j < 16; ++j)
            tmp[j] = f2bf(xs[(l16 << 4) + j][n] * rsv);
        *(short8*)(op + (size_t)n * 256 + (l16 << 4)) = *(const short8*)(&tmp[0]);
        *(short8*)(op + (size_t)n * 256 + (l16 << 4) + 8) = *(const short8*)(&tmp[8]);
    }
}

// ---------------- K2: tb[b][c][n] = nrm[n]*(W xn)[c,n] + bias[c] ------------
__global__ __launch_bounds__(256) void k_tgemm(const u16* __restrict__ Wbf,
                                               const u16* __restrict__ xfn,
                                               const float* __restrict__ bias,
                                               const float* __restrict__ nrm,
                                               u16* __restrict__ tb) {
    int bid = blockIdx.x;
    int batch = bid >> 7, nt = bid & 127;
    int n0 = nt << 5;
    const u16* xf_b = xfn + ((size_t)batch << 20);
    u16* tb_b = tb + ((size_t)batch << 20);
    int tid = threadIdx.x, wid = tid >> 6, lane = tid & 63, lg = lane >> 4, lr = lane & 15;

    f32x4 zero = {0.f, 0.f, 0.f, 0.f};
    f32x4 acc[4][2];
#pragma unroll
    for (int ci = 0; ci < 4; ++ci)
#pragma unroll
        for (int nj = 0; nj < 2; ++nj) acc[ci][nj] = zero;

#pragma unroll
    for (int kc = 0; kc < 8; ++kc) {
        short8 bfr[2], afr[4];
#pragma unroll
        for (int nj = 0; nj < 2; ++nj)
            bfr[nj] = *(const short8*)(xf_b + (size_t)(n0 + (nj << 4) + lr) * 256 + (kc << 5) + (lg << 3));
#pragma unroll
        for (int ci = 0; ci < 4; ++ci)
            afr[ci] = *(const short8*)(Wbf + (size_t)((wid << 6) + (ci << 4) + lr) * 256 + (kc << 5) + (lg << 3));
#pragma unroll
        for (int ci = 0; ci < 4; ++ci) {
            acc[ci][0] = MFMA16(afr[ci], bfr[0], acc[ci][0]);
            acc[ci][1] = MFMA16(afr[ci], bfr[1], acc[ci][1]);
        }
    }
    float nrmv[2];
#pragma unroll
    for (int nj = 0; nj < 2; ++nj)
        nrmv[nj] = nrm[(batch << 12) + n0 + (nj << 4) + lr];
#pragma unroll
    for (int ci = 0; ci < 4; ++ci) {
        int cb = (wid << 6) + (ci << 4) + (lg << 2);
#pragma unroll
        for (int r = 0; r < 4; ++r) {
            float bv = bias[cb + r];
#pragma unroll
            for (int nj = 0; nj < 2; ++nj)
                tb_b[(size_t)(cb + r) * 4096 + n0 + (nj << 4) + lr] = f2bf(acc[ci][nj][r] * nrmv[nj] + bv);
        }
    }
}

// ---------------- K3: fused  O[:,ntile] = T * P^T  --------------------------
// 256 blocks (1/CU), 512 threads (8 waves). BN=BM=64.
// LDS = swizzled P dbuf ONLY. Stage-A B-fragments from L2 into regs,
// double-buffered 2 iters ahead; tb fragments double-buffered 1 iter ahead.
// NOTHING loaded in a body is consumed in that body -> the compiler's vmcnt
// waits are vmcnt(this-body's-count), never a drain; one lgkm-only barrier/iter.
__global__ __launch_bounds__(512, 2) void k_fused(const u16* __restrict__ xfn,
                                                  const u16* __restrict__ tb,
                                                  float* __restrict__ out) {
    __shared__ __align__(16) u16 lds_p[2][4096];   // P dbuf, 64x64, swizzled

#define PBYTE(row, col) ((((row) << 7) + ((col) << 1)) ^ (((row) & 7) << 4))

    int bid = blockIdx.x;
    // XCD swizzle: batch b's 64 blocks -> XCDs {2b, 2b+1} (L2-resident panels)
    int xcd = bid & 7, grp = bid >> 3;
    int batch = xcd >> 1;
    int nt = grp + 32 * (xcd & 1);
    int n0 = nt << 6;

    const u16* xf_b = xfn + ((size_t)batch << 20);
    const u16* tb_b = tb + ((size_t)batch << 20);
    float* out_b = out + ((size_t)batch << 20);

    int tid = threadIdx.x;
    int wid = tid >> 6, lane = tid & 63, lg = lane >> 4, lr = lane & 15;
    int rt2 = wid >> 2, tc = wid & 3;   // stage A roles: row-half, col-tile
    // stage B role: wave wid owns c rows [32*wid, 32*wid+32)

    // persistent A fragments: block's 64 n-rows, full K=256 (64 VGPRs)
    short8 afrag[2][8];
#pragma unroll
    for (int ri = 0; ri < 2; ++ri) {
        const u16* p = xf_b + (size_t)(n0 + (rt2 << 5) + (ri << 4) + lr) * 256 + (lg << 3);
#pragma unroll
        for (int kc = 0; kc < 8; ++kc) afrag[ri][kc] = *(const short8*)(p + (kc << 5));
    }
    // stage-A B-fragment base: row (tc<<4)+lr of the m-tile, 16B at lg*16B
    const u16* bfp = xf_b + (size_t)((tc << 4) + lr) * 256 + (lg << 3);

    // prologue: bf0 = m-tile 0 fragments; bfA = m-tile 1; tbA = tb[0]
    short8 bf0[8], bfA[8], bfB[8];
#pragma unroll
    for (int kc = 0; kc < 8; ++kc) bf0[kc] = *(const short8*)(bfp + (kc << 5));
#pragma unroll
    for (int kc = 0; kc < 8; ++kc) bfA[kc] = *(const short8*)(bfp + (64 << 8) + (kc << 5));
    short8 tbA[2][2], tbB[2][2];
#pragma unroll
    for (int ci = 0; ci < 2; ++ci)
#pragma unroll
        for (int k2 = 0; k2 < 2; ++k2)
            tbA[ci][k2] = *(const short8*)(tb_b + (size_t)((wid << 5) + (ci << 4) + lr) * 4096
                                           + (k2 << 5) + (lg << 3));

    f32x4 zero = {0.f, 0.f, 0.f, 0.f};
    f32x4 oacc[2][4];
#pragma unroll
    for (int ci = 0; ci < 2; ++ci)
#pragma unroll
        for (int nj = 0; nj < 4; ++nj) oacc[ci][nj] = zero;

    // prologue: S[0] -> P[0] -> lds_p[0]
    {
        f32x4 sacc0 = zero, sacc1 = zero;
#pragma unroll
        for (int kc = 0; kc < 8; ++kc) {
            sacc0 = MFMA16(afrag[0][kc], bf0[kc], sacc0);
            sacc1 = MFMA16(afrag[1][kc], bf0[kc], sacc1);
        }
        char* pn = (char*)&lds_p[0][0];
        int colw = (tc << 4) + lr;
#pragma unroll
        for (int r = 0; r < 4; ++r) {
            int row0 = (rt2 << 5) + (lg << 2) + r;
            float s0 = fmaxf(sacc0[r], 0.f);
            *(u16*)(pn + PBYTE(row0, colw)) = f2bf(s0 * s0);
            float s1 = fmaxf(sacc1[r], 0.f);
            *(u16*)(pn + PBYTE(row0 + 16, colw)) = f2bf(s1 * s1);
        }
    }
    asm volatile("s_waitcnt lgkmcnt(0)" ::: "memory");
    __builtin_amdgcn_sched_barrier(0);
    __builtin_amdgcn_s_barrier();
    __builtin_amdgcn_sched_barrier(0);

// FBODY(MT, CUR, BFC, BFN, TBC, TBN): consumes P[MT] (lds_p[CUR]) with TBC
// (=tb[MT], loaded last iter) into oacc; computes S[MT+1] from BFC (loaded 2
// iters ago) -> lds_p[CUR^1]; prefetches bf[MT+2] -> BFN, tb[MT+1] -> TBN.
#define FBODY(MT, CUR, BFC, BFN, TBC, TBN)                                                 \
    {                                                                                      \
        if ((MT) <= 61) {                                                                  \
            _Pragma("unroll")                                                              \
            for (int kc = 0; kc < 8; ++kc)                                                 \
                BFN[kc] = *(const short8*)(bfp + ((size_t)((MT) + 2) << 14) + (kc << 5));  \
        }                                                                                  \
        if ((MT) <= 62) {                                                                  \
            _Pragma("unroll")                                                              \
            for (int ci = 0; ci < 2; ++ci) {                                               \
                _Pragma("unroll")                                                          \
                for (int k2 = 0; k2 < 2; ++k2)                                             \
                    TBN[ci][k2] = *(const short8*)(tb_b                                    \
                        + (size_t)((wid << 5) + (ci << 4) + lr) * 4096                     \
                        + (((MT) + 1) << 6) + (k2 << 5) + (lg << 3));                      \
            }                                                                              \
        }                                                                                  \
        char* pc = (char*)&lds_p[CUR][0];                                                  \
        char* pn = (char*)&lds_p[(CUR) ^ 1][0];                                            \
        short8 pfr[4][2];                                                                  \
        _Pragma("unroll")                                                                  \
        for (int nj = 0; nj < 4; ++nj) {                                                   \
            _Pragma("unroll")                                                              \
            for (int k2 = 0; k2 < 2; ++k2)                                                 \
                pfr[nj][k2] = *(const short8*)(pc + PBYTE((nj << 4) + lr,                  \
                                                          (k2 << 5) + (lg << 3)));        \
        }                                                                                  \
        if ((MT) <= 62) { /* compute S[MT+1] from BFC (2-iter-old regs) */                 \
            f32x4 sacc0 = zero, sacc1 = zero;                                              \
            _Pragma("unroll")                                                              \
            for (int kc = 0; kc < 8; ++kc) {                                               \
                sacc0 = MFMA16(afrag[0][kc], BFC[kc], sacc0);                              \
                sacc1 = MFMA16(afrag[1][kc], BFC[kc], sacc1);                              \
            }                                                                              \
            int colw = (tc << 4) + lr;                                                     \
            _Pragma("unroll")                                                              \
            for (int r = 0; r < 4; ++r) {                                                  \
                int row0 = (rt2 << 5) + (lg << 2) + r;                                     \
                float s0 = fmaxf(sacc0[r], 0.f);                                           \
                *(u16*)(pn + PBYTE(row0, colw)) = f2bf(s0 * s0);                           \
                float s1 = fmaxf(sacc1[r], 0.f);                                           \
                *(u16*)(pn + PBYTE(row0 + 16, colw)) = f2bf(s1 * s1);                      \
            }                                                                              \
        }                                                                                  \
        _Pragma("unroll")                                                                  \
        for (int ci = 0; ci < 2; ++ci) {                                                   \
            _Pragma("unroll")                                                              \
            for (int nj = 0; nj < 4; ++nj) {                                               \
                oacc[ci][nj] = MFMA16(TBC[ci][0], pfr[nj][0], oacc[ci][nj]);               \
                oacc[ci][nj] = MFMA16(TBC[ci][1], pfr[nj][1], oacc[ci][nj]);               \
            }                                                                              \
        }                                                                                  \
        asm volatile("s_waitcnt lgkmcnt(0)" ::: "memory");                                 \
        __builtin_amdgcn_sched_barrier(0);                                                 \
        __builtin_amdgcn_s_barrier();                                                      \
        __builtin_amdgcn_sched_barrier(0);                                                 \
    }

    for (int t = 0; t < 64; t += 2) {
        FBODY(t, 0, bfA, bfB, tbA, tbB);
        FBODY(t + 1, 1, bfB, bfA, tbB, tbA);
    }
#undef FBODY
#undef PBYTE

    // ---- epilogue: write O fp32 ----
#pragma unroll
    for (int ci = 0; ci < 2; ++ci) {
        int c = (wid << 5) + (ci << 4) + (lg << 2);
#pragma unroll
        for (int nj = 0; nj < 4; ++nj) {
            int n = n0 + (nj << 4) + lr;
            float* op = out_b + (size_t)c * 4096 + n;
#pragma unroll
            for (int r = 0; r < 4; ++r) op[(size_t)r * 4096] = oacc[ci][nj][r];
        }
    }
}

extern "C" void kernel_launch(void* const* d_in, const int* in_sizes, int n_in,
                              void* d_out, int out_size, void* d_ws, size_t ws_size,
                              hipStream_t stream) {
    const float* x = (const float*)d_in[0];     // (4,256,16,16,16) fp32
    const float* W = (const float*)d_in[1];     // (256,256) fp32
    const float* bias = (const float*)d_in[2];  // (256,) fp32
    float* out = (float*)d_out;

    char* ws = (char*)d_ws;
    u16* xfn = (u16*)ws;                                   // 8 MiB: [B][N][C] bf16, normalized
    u16* tb = (u16*)(ws + ((size_t)8 << 20));              // 8 MiB: [B][C][N] bf16
    u16* Wbf = (u16*)(ws + ((size_t)16 << 20));            // 128 KiB
    float* nrm = (float*)(ws + ((size_t)16 << 20) + (192u << 10));  // 64 KiB

    hipLaunchKernelGGL(k_prep, dim3(256), dim3(256), 0, stream, x, W, xfn, Wbf, nrm);
    hipLaunchKernelGGL(k_tgemm, dim3(512), dim3(256), 0, stream, Wbf, xfn, bias, nrm, tb);
    hipLaunchKernelGGL(k_fused, dim3(256), dim3(512), 0, stream, xfn, tb, out);
}

// Round 6
// 156.408 us; speedup vs baseline: 1.6823x; 1.6823x over previous
//
#include <hip/hip_runtime.h>
#include <hip/hip_bf16.h>

// Problem: B=4, C=256, N=4096 (16^3).
// out[b,c,n] = sum_m relu(cos(x_n,x_m))^2 * (W x + b)[c,m]
// Decomposition: xn = x/||x|| (bf16) -> S = xn^T xn, P = relu(S)^2,
//                T[c,m] = nrm[m]*(W xn)[c,m] + b[c],   out = T * P^T.
// k_fused uses producer/consumer wave specialization: 4 S-waves (each owns a
// 16-m col-tile, reads its UNIQUE xfn rows direct from L2 -> no LDS broadcast)
// and 4 O-waves (each owns 64 c-rows, unique tb reads). Only P (8KB/iter)
// crosses waves, via a swizzled LDS double buffer.

typedef unsigned short u16;
typedef __attribute__((ext_vector_type(8))) short short8;   // 8 bf16 = 4 VGPRs
typedef __attribute__((ext_vector_type(4))) float f32x4;

#define MFMA16(a, b, c) __builtin_amdgcn_mfma_f32_16x16x32_bf16((a), (b), (c), 0, 0, 0)

__device__ __forceinline__ u16 f2bf(float f) {
    union { float f; unsigned u; } v; v.f = f;
    unsigned u = v.u;
    u += 0x7fffu + ((u >> 16) & 1u);   // RNE
    return (u16)(u >> 16);
}

// ------- K1: fused norm + transpose + W-convert: one read of x ---------------
__global__ __launch_bounds__(256) void k_prep(const float* __restrict__ x,
                                              const float* __restrict__ W,
                                              u16* __restrict__ xfn,
                                              u16* __restrict__ Wbf,
                                              float* __restrict__ nrm) {
    __shared__ float xs[256][65];     // 65 pad: conflict-free col reads
    __shared__ float part[4][64];
    __shared__ float rs_s[64];
    int bid = blockIdx.x;
    int b = bid >> 6, n0 = (bid & 63) << 6;
    int tid = threadIdx.x;
    int wi = (bid << 8) + tid;
    Wbf[wi] = f2bf(W[wi]);
    int rowg = tid >> 4, l16 = tid & 15;
    const float* xb = x + ((size_t)b << 20) + n0;
#pragma unroll
    for (int s = 0; s < 16; ++s) {
        int row = (s << 4) + rowg;    // c index
        float4 v = *(const float4*)(xb + (size_t)row * 4096 + (l16 << 2));
        xs[row][(l16 << 2) + 0] = v.x;
        xs[row][(l16 << 2) + 1] = v.y;
        xs[row][(l16 << 2) + 2] = v.z;
        xs[row][(l16 << 2) + 3] = v.w;
    }
    __syncthreads();
    int q = tid >> 6, nl = tid & 63;
    float ss = 0.f;
#pragma unroll 16
    for (int c = 0; c < 64; ++c) {
        float v = xs[(q << 6) + c][nl];
        ss += v * v;
    }
    part[q][nl] = ss;
    __syncthreads();
    if (tid < 64) {
        float t = part[0][tid] + part[1][tid] + part[2][tid] + part[3][tid];
        float nr = sqrtf(t);
        nrm[(b << 12) + n0 + tid] = nr;
        rs_s[tid] = 1.0f / fmaxf(nr, 1e-8f);
    }
    __syncthreads();
    u16* op = xfn + ((size_t)b << 20) + (size_t)n0 * 256;
#pragma unroll
    for (int s2 = 0; s2 < 4; ++s2) {
        int n = (s2 << 4) + rowg;
        float rsv = rs_s[n];
        u16 tmp[16];
#pragma unroll
        for (int j = 0; j < 16; ++j)
            tmp[j] = f2bf(xs[(l16 << 4) + j][n] * rsv);
        *(short8*)(op + (size_t)n * 256 + (l16 << 4)) = *(const short8*)(&tmp[0]);
        *(short8*)(op + (size_t)n * 256 + (l16 << 4) + 8) = *(const short8*)(&tmp[8]);
    }
}

// ---------------- K2: tb[b][c][n] = nrm[n]*(W xn)[c,n] + bias[c] ------------
__global__ __launch_bounds__(256) void k_tgemm(const u16* __restrict__ Wbf,
                                               const u16* __restrict__ xfn,
                                               const float* __restrict__ bias,
                                               const float* __restrict__ nrm,
                                               u16* __restrict__ tb) {
    int bid = blockIdx.x;
    int batch = bid >> 7, nt = bid & 127;
    int n0 = nt << 5;
    const u16* xf_b = xfn + ((size_t)batch << 20);
    u16* tb_b = tb + ((size_t)batch << 20);
    int tid = threadIdx.x, wid = tid >> 6, lane = tid & 63, lg = lane >> 4, lr = lane & 15;

    f32x4 zero = {0.f, 0.f, 0.f, 0.f};
    f32x4 acc[4][2];
#pragma unroll
    for (int ci = 0; ci < 4; ++ci)
#pragma unroll
        for (int nj = 0; nj < 2; ++nj) acc[ci][nj] = zero;

#pragma unroll
    for (int kc = 0; kc < 8; ++kc) {
        short8 bfr[2], afr[4];
#pragma unroll
        for (int nj = 0; nj < 2; ++nj)
            bfr[nj] = *(const short8*)(xf_b + (size_t)(n0 + (nj << 4) + lr) * 256 + (kc << 5) + (lg << 3));
#pragma unroll
        for (int ci = 0; ci < 4; ++ci)
            afr[ci] = *(const short8*)(Wbf + (size_t)((wid << 6) + (ci << 4) + lr) * 256 + (kc << 5) + (lg << 3));
#pragma unroll
        for (int ci = 0; ci < 4; ++ci) {
            acc[ci][0] = MFMA16(afr[ci], bfr[0], acc[ci][0]);
            acc[ci][1] = MFMA16(afr[ci], bfr[1], acc[ci][1]);
        }
    }
    float nrmv[2];
#pragma unroll
    for (int nj = 0; nj < 2; ++nj)
        nrmv[nj] = nrm[(batch << 12) + n0 + (nj << 4) + lr];
#pragma unroll
    for (int ci = 0; ci < 4; ++ci) {
        int cb = (wid << 6) + (ci << 4) + (lg << 2);
#pragma unroll
        for (int r = 0; r < 4; ++r) {
            float bv = bias[cb + r];
#pragma unroll
            for (int nj = 0; nj < 2; ++nj)
                tb_b[(size_t)(cb + r) * 4096 + n0 + (nj << 4) + lr] = f2bf(acc[ci][nj][r] * nrmv[nj] + bv);
        }
    }
}

// ---------------- K3: fused  O[:,ntile] = T * P^T  --------------------------
// 256 blocks (1/CU), 512 threads (8 waves). BN(n-tile)=BM(m-step)=64.
// Waves 0-3: producers. Wave tc owns S cols [16tc,16tc+16): afrag = all 64 n
// rows (128 VGPR, persistent); streams its UNIQUE 16 m-rows of xfn from L2
// (reg-dbuf, 1 iter ahead); writes P[n][m] cols into swizzled lds_p dbuf.
// Waves 4-7: consumers. Wave cq owns c rows [64cq,64cq+64): reads P from
// lds_p (only consumers read: 32KB/iter), tb fragments from L2 (reg-dbuf,
// unique rows); accumulates oacc over all 64 m-tiles; writes out at end.
// One lgkm-only barrier per iter; global prefetches are never drained.
__global__ __launch_bounds__(512) void k_fused(const u16* __restrict__ xfn,
                                               const u16* __restrict__ tb,
                                               float* __restrict__ out) {
    __shared__ __align__(16) u16 lds_p[2][4096];   // P dbuf, 64x64, swizzled

#define PBYTE(row, col) ((((row) << 7) + ((col) << 1)) ^ (((row) & 7) << 4))
#define BAR() do { asm volatile("s_waitcnt lgkmcnt(0)" ::: "memory");              \
    __builtin_amdgcn_sched_barrier(0); __builtin_amdgcn_s_barrier();               \
    __builtin_amdgcn_sched_barrier(0); } while (0)

    int bid = blockIdx.x;
    // XCD swizzle: batch b's 64 blocks -> XCDs {2b, 2b+1} (L2-resident panels)
    int xcd = bid & 7, grp = bid >> 3;
    int batch = xcd >> 1;
    int nt = grp + 32 * (xcd & 1);
    int n0 = nt << 6;

    const u16* xf_b = xfn + ((size_t)batch << 20);
    const u16* tb_b = tb + ((size_t)batch << 20);
    float* out_b = out + ((size_t)batch << 20);

    int tid = threadIdx.x;
    int wid = tid >> 6, lane = tid & 63, lg = lane >> 4, lr = lane & 15;
    f32x4 zero = {0.f, 0.f, 0.f, 0.f};

    if (wid < 4) {
        // ================= producer: S / P =================
        int tc = wid;
        // afrag: A-operand rows n0..n0+63, full K=256 (128 VGPR persistent)
        short8 afrag[4][8];
#pragma unroll
        for (int rt = 0; rt < 4; ++rt)
#pragma unroll
            for (int kc = 0; kc < 8; ++kc)
                afrag[rt][kc] = *(const short8*)(xf_b + (size_t)(n0 + (rt << 4) + lr) * 256
                                                 + (kc << 5) + (lg << 3));
        // streamed B rows: m = 64*tile + 16*tc + lr  (unique per wave)
        const u16* bp = xf_b + (size_t)((tc << 4) + lr) * 256 + (lg << 3);
        short8 bfrA[8], bfrB[8];
#pragma unroll
        for (int kc = 0; kc < 8; ++kc) bfrA[kc] = *(const short8*)(bp + (kc << 5));
#pragma unroll
        for (int kc = 0; kc < 8; ++kc) bfrB[kc] = *(const short8*)(bp + (1 << 14) + (kc << 5));

#define SCOMP(BUF, PB)                                                                     \
    {                                                                                      \
        f32x4 sa0 = zero, sa1 = zero, sa2 = zero, sa3 = zero;                              \
        _Pragma("unroll")                                                                  \
        for (int kc = 0; kc < 8; ++kc) {                                                   \
            sa0 = MFMA16(afrag[0][kc], BUF[kc], sa0);                                      \
            sa1 = MFMA16(afrag[1][kc], BUF[kc], sa1);                                      \
            sa2 = MFMA16(afrag[2][kc], BUF[kc], sa2);                                      \
            sa3 = MFMA16(afrag[3][kc], BUF[kc], sa3);                                      \
        }                                                                                  \
        char* pd = (char*)&lds_p[PB][0];                                                   \
        int colw = (tc << 4) + lr;                                                         \
        _Pragma("unroll")                                                                  \
        for (int r = 0; r < 4; ++r) {                                                      \
            int rw = (lg << 2) + r;                                                        \
            float v0 = fmaxf(sa0[r], 0.f);                                                 \
            *(u16*)(pd + PBYTE(rw, colw)) = f2bf(v0 * v0);                                 \
            float v1 = fmaxf(sa1[r], 0.f);                                                 \
            *(u16*)(pd + PBYTE(rw + 16, colw)) = f2bf(v1 * v1);                            \
            float v2 = fmaxf(sa2[r], 0.f);                                                 \
            *(u16*)(pd + PBYTE(rw + 32, colw)) = f2bf(v2 * v2);                            \
            float v3 = fmaxf(sa3[r], 0.f);                                                 \
            *(u16*)(pd + PBYTE(rw + 48, colw)) = f2bf(v3 * v3);                            \
        }                                                                                  \
    }

        // prologue: P[0] from bfrA -> buf0
        SCOMP(bfrA, 0);
        BAR();

// SBODY(T, BC, BN): BC holds m-tile T+1 -> compute P[T+1] -> buf (T+1)&1;
// prefetch m-tile T+2 -> BN. Loads issued first for a full body of cover.
#define SBODY(T, BC, BN)                                                                   \
    {                                                                                      \
        if ((T) <= 61) {                                                                   \
            _Pragma("unroll")                                                              \
            for (int kc = 0; kc < 8; ++kc)                                                 \
                BN[kc] = *(const short8*)(bp + ((size_t)((T) + 2) << 14) + (kc << 5));     \
        }                                                                                  \
        if ((T) < 63) SCOMP(BC, ((T) + 1) & 1);                                            \
        BAR();                                                                             \
    }

        for (int t = 0; t < 64; t += 2) {
            SBODY(t, bfrB, bfrA);
            SBODY(t + 1, bfrA, bfrB);
        }
#undef SBODY
#undef SCOMP
    } else {
        // ================= consumer: O += T * P^T =================
        int cq = wid - 4;
        const u16* tp = tb_b + (size_t)((cq << 6) + lr) * 4096 + (lg << 3);
        short8 tbcA[4][2], tbcB[4][2];
#pragma unroll
        for (int ci = 0; ci < 4; ++ci)
#pragma unroll
            for (int k2 = 0; k2 < 2; ++k2)
                tbcA[ci][k2] = *(const short8*)(tp + (size_t)(ci << 4) * 4096 + (k2 << 5));

        f32x4 oacc[4][4];
#pragma unroll
        for (int ci = 0; ci < 4; ++ci)
#pragma unroll
            for (int nj = 0; nj < 4; ++nj) oacc[ci][nj] = zero;
        BAR();

// OBODY(T, TC, TN): consume P[T] (lds_p[T&1]) with TC (=tb tile T) into oacc;
// prefetch tb tile T+1 -> TN.
#define OBODY(T, TC, TN)                                                                   \
    {                                                                                      \
        if ((T) <= 62) {                                                                   \
            _Pragma("unroll")                                                              \
            for (int ci = 0; ci < 4; ++ci) {                                               \
                _Pragma("unroll")                                                          \
                for (int k2 = 0; k2 < 2; ++k2)                                             \
                    TN[ci][k2] = *(const short8*)(tp + (size_t)(ci << 4) * 4096            \
                                                  + (((T) + 1) << 6) + (k2 << 5));        \
            }                                                                              \
        }                                                                                  \
        char* pc = (char*)&lds_p[(T) & 1][0];                                              \
        short8 pfr[4][2];                                                                  \
        _Pragma("unroll")                                                                  \
        for (int nj = 0; nj < 4; ++nj) {                                                   \
            _Pragma("unroll")                                                              \
            for (int k2 = 0; k2 < 2; ++k2)                                                 \
                pfr[nj][k2] = *(const short8*)(pc + PBYTE((nj << 4) + lr,                  \
                                                          (k2 << 5) + (lg << 3)));        \
        }                                                                                  \
        _Pragma("unroll")                                                                  \
        for (int ci = 0; ci < 4; ++ci) {                                                   \
            _Pragma("unroll")                                                              \
            for (int nj = 0; nj < 4; ++nj) {                                               \
                oacc[ci][nj] = MFMA16(TC[ci][0], pfr[nj][0], oacc[ci][nj]);                \
                oacc[ci][nj] = MFMA16(TC[ci][1], pfr[nj][1], oacc[ci][nj]);                \
            }                                                                              \
        }                                                                                  \
        BAR();                                                                             \
    }

        for (int t = 0; t < 64; t += 2) {
            OBODY(t, tbcA, tbcB);
            OBODY(t + 1, tbcB, tbcA);
        }
#undef OBODY

        // epilogue: write O fp32
#pragma unroll
        for (int ci = 0; ci < 4; ++ci) {
            int c = (cq << 6) + (ci << 4) + (lg << 2);
#pragma unroll
            for (int nj = 0; nj < 4; ++nj) {
                int n = n0 + (nj << 4) + lr;
                float* op = out_b + (size_t)c * 4096 + n;
#pragma unroll
                for (int r = 0; r < 4; ++r) op[(size_t)r * 4096] = oacc[ci][nj][r];
            }
        }
    }
#undef PBYTE
#undef BAR
}

extern "C" void kernel_launch(void* const* d_in, const int* in_sizes, int n_in,
                              void* d_out, int out_size, void* d_ws, size_t ws_size,
                              hipStream_t stream) {
    const float* x = (const float*)d_in[0];     // (4,256,16,16,16) fp32
    const float* W = (const float*)d_in[1];     // (256,256) fp32
    const float* bias = (const float*)d_in[2];  // (256,) fp32
    float* out = (float*)d_out;

    char* ws = (char*)d_ws;
    u16* xfn = (u16*)ws;                                   // 8 MiB: [B][N][C] bf16, normalized
    u16* tb = (u16*)(ws + ((size_t)8 << 20));              // 8 MiB: [B][C][N] bf16
    u16* Wbf = (u16*)(ws + ((size_t)16 << 20));            // 128 KiB
    float* nrm = (float*)(ws + ((size_t)16 << 20) + (192u << 10));  // 64 KiB

    hipLaunchKernelGGL(k_prep, dim3(256), dim3(256), 0, stream, x, W, xfn, Wbf, nrm);
    hipLaunchKernelGGL(k_tgemm, dim3(512), dim3(256), 0, stream, Wbf, xfn, bias, nrm, tb);
    hipLaunchKernelGGL(k_fused, dim3(256), dim3(512), 0, stream, xfn, tb, out);
}